// Round 13
// baseline (69.490 us; speedup 1.0000x reference)
//
#include <hip/hip_runtime.h>

#define NQ 12
#define NL 4
#define DIM 4096
#define BLOCK 512
#define PER_T 8           // amplitudes per thread
#define BATCH 256

// Layout A: i = lane | k<<6 | wv<<9   (lane: q6-11, k: q3-5, wv: q0-2)
// Layout B: i = lane | wv<<6 | k<<9   (lane: q6-11, wv: q3-5, k: q0-2)
// Qubit q lives at bit position 11-q of the global amplitude index.
//
// Staging bit-permutations (store-address maps) to vectorize the 2-pt folds:
//   pass1 fold bit = bit5  -> s1(i): bit5->bit0, bits0-4 -> 1-5
//   pass2 fold bit = bit4  -> s2(i): bit4->bit0, bits0-3 -> 1-4, bit5 stays
// Each fold pair {idx, idx^foldbit} becomes adjacent float2 -> one aligned
// ds_read_b128. DS ops/thread/layer: 16 b64 writes + 16 b128 reads = 32
// (was 48). All address sets remain lane-bijective / broadcast-paired ->
// conflict-free.

__device__ __forceinline__ float2 cmul(float2 a, float2 b) {
    return make_float2(a.x * b.x - a.y * b.y, a.x * b.y + a.y * b.x);
}
__device__ __forceinline__ float2 cconj(float2 a) { return make_float2(a.x, -a.y); }

// HW sincos (revolutions, fract-reduced); |err| ~1e-6 << 1.37e-2 threshold.
__device__ __forceinline__ float2 fsincos(float ang) {   // (cos, sin)
    float r = ang * 0.15915494309189535f;
    r = r - floorf(r);
    return make_float2(__builtin_amdgcn_cosf(r), __builtin_amdgcn_sinf(r));
}

// ---- DPP lane exchanges (VALU pipe, intrinsic-only) -----------------------
// quad_perm xor1 = 0xB1, xor2 = 0x4E, xor3 = 0x1B; row_ror:8 = xor8 = 0x128;
// row_half_mirror = xor7 = 0x141.  xor4 = 0x141 then 0x1B.
template <int CTRL>
__device__ __forceinline__ float dppx(float v) {
    int i = __builtin_bit_cast(int, v);
    int r = __builtin_amdgcn_update_dpp(0, i, CTRL, 0xF, 0xF, true);
    return __builtin_bit_cast(float, r);
}
template <int MSK, int CTRL>
__device__ __forceinline__ void ry_dpp(float2* psi, int lane, float c, float s) {
    const float se = (lane & MSK) ? s : -s;
#pragma unroll
    for (int k = 0; k < PER_T; ++k) {
        float px = dppx<CTRL>(psi[k].x);
        float py = dppx<CTRL>(psi[k].y);
        psi[k].x = c * psi[k].x + se * px;
        psi[k].y = c * psi[k].y + se * py;
    }
}
__device__ __forceinline__ void ry_dpp4(float2* psi, int lane, float c, float s) {
    const float se = (lane & 4) ? s : -s;
#pragma unroll
    for (int k = 0; k < PER_T; ++k) {
        float px = dppx<0x1B>(dppx<0x141>(psi[k].x));
        float py = dppx<0x1B>(dppx<0x141>(psi[k].y));
        psi[k].x = c * psi[k].x + se * px;
        psi[k].y = c * psi[k].y + se * py;
    }
}

// staging bit-permutations (index in float2 units)
__device__ __forceinline__ int s1map(int i) {      // bit5 -> bit0
    return (i & ~0x3F) | ((i & 0x1F) << 1) | ((i >> 5) & 1);
}
__device__ __forceinline__ int s2map(int i) {      // bit4 -> bit0, bit5 stays
    return (i & ~0x3F) | (i & 0x20) | ((i & 0xF) << 1) | ((i >> 4) & 1);
}

__global__ __launch_bounds__(BLOCK, 2) void qcp_kernel(
    const float* __restrict__ x,      // (BATCH, NQ)
    const float* __restrict__ w,      // (NL, NQ, 2) flat: [ry, rz] -> 96
    float* __restrict__ out)          // (BATCH,)
{
    __shared__ float4 sP[DIM / 2];         // pass-1 staging (16B-aligned)
    __shared__ float4 sQ[DIM / 2];         // pass-2 staging
    __shared__ float2 trig[NL * NQ * 2];   // (cos, sin) of 0.5*w[idx]
    __shared__ float  zhalf[NL * NQ];      // 0.5 * rz weight
    __shared__ float  rbuf[8];

    float2* sPf2 = (float2*)sP;
    float2* sQf2 = (float2*)sQ;

    const int b    = blockIdx.x;
    const int t    = threadIdx.x;
    const int lane = t & 63;
    const int wv   = t >> 6;               // 0..7

    if (t < NL * NQ * 2) trig[t] = fsincos(0.5f * w[t]);
    if (t < NL * NQ) zhalf[t] = 0.5f * w[2 * t + 1];

    float xr[NQ];
#pragma unroll
    for (int q = 0; q < NQ; ++q) xr[q] = x[b * NQ + q];

    // Thread-constant addresses (sigma-transformed).
    int wA[PER_T], rB[PER_T], wB[PER_T], rG[PER_T];
#pragma unroll
    for (int k = 0; k < PER_T; ++k) {
        int iA = lane | (k << 6) | (wv << 9);
        int iB = lane | (wv << 6) | (k << 9);
        int gI = iA ^ (iA >> 1);
        wA[k] = s1map(iA);          // pass-1 store (float2 idx)
        rB[k] = s1map(iB) >> 1;     // pass-1 load  (float4 idx; pair {iB, iB^32})
        wB[k] = s2map(iB);          // pass-2 store (float2 idx)
        rG[k] = s2map(gI) >> 1;     // pass-2 load  (float4 idx; pair {gI, gI^16})
    }

    // Data-encoding phasors for the layout-A set (identical each layer).
    float2 eph[PER_T];
#pragma unroll
    for (int k = 0; k < PER_T; ++k) {
        int j = lane | (k << 6) | (wv << 9);
        float ang = 0.0f;
#pragma unroll
        for (int q = 0; q < NQ; ++q)
            ang += ((j >> (NQ - 1 - q)) & 1) ? 0.5f * xr[q] : -0.5f * xr[q];
        eph[k] = fsincos(ang);
    }

    float2 psi[PER_T];
#pragma unroll
    for (int k = 0; k < PER_T; ++k) psi[k] = make_float2(0.015625f, 0.0f);

    __syncthreads();   // trig/zhalf ready

    for (int l = 0; l < NL; ++l) {
        // ---- 0) layer coefficients -----------------------------------------
        float2 tRY[9];          // RY (c,s) for q=3..11
        float2 tRY0[3], tZ0[3]; // q=0..2 RY and RZ pairs
        float  zh[4];           // 0.5*rz for q=8..11
        float2 z3, z4, z5;      // e^{i*0.5*rz} for q=3..5
        float2 z6, z7;          // e^{i*0.5*rz} for q=6, q=7 (fold phases)
#pragma unroll
        for (int q = 3; q <= 11; ++q) tRY[q - 3] = trig[(l * NQ + q) * 2];
#pragma unroll
        for (int q = 0; q < 3; ++q) {
            tRY0[q] = trig[(l * NQ + q) * 2 + 0];
            tZ0[q]  = trig[(l * NQ + q) * 2 + 1];
        }
        z3 = trig[(l * NQ + 3) * 2 + 1];
        z4 = trig[(l * NQ + 4) * 2 + 1];
        z5 = trig[(l * NQ + 5) * 2 + 1];
        z6 = trig[(l * NQ + 6) * 2 + 1];
        z7 = trig[(l * NQ + 7) * 2 + 1];
#pragma unroll
        for (int q = 8; q <= 11; ++q) zh[q - 8] = zhalf[l * NQ + q];

        // ---- 1) diagonal data-encoding phase (layout A) --------------------
#pragma unroll
        for (int k = 0; k < PER_T; ++k) psi[k] = cmul(psi[k], eph[k]);

        // ---- 2) RY q3..5 on k bits (q3<->kb2, q4<->kb1, q5<->kb0) ----------
#pragma unroll
        for (int q = 3; q <= 5; ++q) {
            const int kb = (11 - q) - 6;
            float c = tRY[q - 3].x, s = tRY[q - 3].y;
#pragma unroll
            for (int m = 0; m < PER_T / 2; ++m) {
                int k0 = ((m >> kb) << (kb + 1)) | (m & ((1 << kb) - 1));
                int k1 = k0 | (1 << kb);
                float2 a0 = psi[k0], a1 = psi[k1];
                psi[k0] = make_float2(c * a0.x - s * a1.x, c * a0.y - s * a1.y);
                psi[k1] = make_float2(s * a0.x + c * a1.x, s * a0.y + c * a1.y);
            }
        }

        // ---- 3) RY q8..11 on lane bits (DPP only) --------------------------
        ry_dpp<8, 0x128>(psi, lane, tRY[5].x, tRY[5].y); // q8  xor8
        ry_dpp4(psi, lane, tRY[6].x, tRY[6].y);          // q9  xor4
        ry_dpp<2, 0x4E>(psi, lane, tRY[7].x, tRY[7].y);  // q10 xor2
        ry_dpp<1, 0xB1>(psi, lane, tRY[8].x, tRY[8].y);  // q11 xor1

        // ---- 4) fused RZ diagonal for q3..5 and q8..11 ---------------------
        // (q6,q7 RZs ride inside the pass folds, after their RYs.)
        float s_lane = 0.0f;
#pragma unroll
        for (int p = 0; p < 4; ++p)          // lane bit p -> qubit 11-p -> zh[3-p]
            s_lane += ((lane >> p) & 1) ? zh[3 - p] : -zh[3 - p];
        {
            float2 base = fsincos(s_lane);
            float2 z45[4];
#pragma unroll
            for (int c2 = 0; c2 < 4; ++c2) {
                float2 a4 = (c2 & 2) ? z4 : cconj(z4);
                float2 a5 = (c2 & 1) ? z5 : cconj(z5);
                z45[c2] = cmul(a4, a5);
            }
#pragma unroll
            for (int k = 0; k < PER_T; ++k) {
                float2 a3 = (k & 4) ? z3 : cconj(z3);
                float2 ph = cmul(cmul(base, a3), z45[k & 3]);
                psi[k] = cmul(psi[k], ph);
            }
        }

        // ---- 5) pass 1: A -> B transpose fused with RY+RZ(q6) --------------
        // b128 read: float4 at rB[k] = pair {bit5=0 (lo), bit5=1 (hi)}.
#pragma unroll
        for (int k = 0; k < PER_T; ++k) sPf2[wA[k]] = psi[k];

        const int   b6  = (lane >> 5) & 1;
        const float c6  = tRY[3].x;
        const float se6 = b6 ? tRY[3].y : -tRY[3].y;
        const float2 zb6 = b6 ? z6 : cconj(z6);
        __syncthreads();
#pragma unroll
        for (int k = 0; k < PER_T; ++k) {
            float4 v = sP[rB[k]];
            float2 lo = make_float2(v.x, v.y);
            float2 hi = make_float2(v.z, v.w);
            float2 own = b6 ? hi : lo;
            float2 oth = b6 ? lo : hi;
            float2 n = make_float2(c6 * own.x + se6 * oth.x,
                                   c6 * own.y + se6 * oth.y);
            psi[k] = cmul(n, zb6);
        }

        // ---- 6) RY+RZ q0..2 on k bits (q0<->kb2, q1<->kb1, q2<->kb0) -------
#pragma unroll
        for (int q = 0; q < 3; ++q) {
            const int kb = 2 - q;
            float c = tRY0[q].x, s = tRY0[q].y;
            float2 z = tZ0[q];
#pragma unroll
            for (int m = 0; m < PER_T / 2; ++m) {
                int k0 = ((m >> kb) << (kb + 1)) | (m & ((1 << kb) - 1));
                int k1 = k0 | (1 << kb);
                float2 a0 = psi[k0], a1 = psi[k1];
                float2 n0 = make_float2(c * a0.x - s * a1.x, c * a0.y - s * a1.y);
                float2 n1 = make_float2(s * a0.x + c * a1.x, s * a0.y + c * a1.y);
                psi[k0] = cmul(n0, cconj(z));
                psi[k1] = cmul(n1, z);
            }
        }

        // ---- 7) pass 2: RY+RZ(q7) + CX ladder + B -> A ---------------------
        // b128 read: float4 at rG[k] = pair {bit4=0 (lo), bit4=1 (hi)};
        // row bit = bit4 of g(j) = lane4 ^ lane5 (thread-uniform).
#pragma unroll
        for (int k = 0; k < PER_T; ++k) sQf2[wB[k]] = psi[k];

        const int   b7  = ((lane >> 4) ^ (lane >> 5)) & 1;
        const float c7  = tRY[4].x;
        const float se7 = b7 ? tRY[4].y : -tRY[4].y;
        const float2 zb7 = b7 ? z7 : cconj(z7);
        __syncthreads();
#pragma unroll
        for (int k = 0; k < PER_T; ++k) {
            float4 v = sQ[rG[k]];
            float2 lo = make_float2(v.x, v.y);
            float2 hi = make_float2(v.z, v.w);
            float2 own = b7 ? hi : lo;
            float2 oth = b7 ? lo : hi;
            float2 n = make_float2(c7 * own.x + se7 * oth.x,
                                   c7 * own.y + se7 * oth.y);
            psi[k] = cmul(n, zb7);
        }
        // Buffer safety: sP reads(l) precede barrier2(l) < sP writes(l+1);
        // sQ reads(l) precede barrier1(l+1) < sQ writes(l+1).
    }

    // ---- <Z(0)>: qubit 0 = bit 11 = wv bit 2 ------------------------------
    float acc = 0.0f;
#pragma unroll
    for (int k = 0; k < PER_T; ++k)
        acc += psi[k].x * psi[k].x + psi[k].y * psi[k].y;
    if (wv >= 4) acc = -acc;
#pragma unroll
    for (int off = 32; off > 0; off >>= 1)
        acc += __shfl_down(acc, off, 64);
    if (lane == 0) rbuf[wv] = acc;
    __syncthreads();
    if (t == 0) {
        float tot = 0.0f;
#pragma unroll
        for (int i = 0; i < 8; ++i) tot += rbuf[i];
        out[b] = tot;
    }
}

extern "C" void kernel_launch(void* const* d_in, const int* in_sizes, int n_in,
                              void* d_out, int out_size, void* d_ws, size_t ws_size,
                              hipStream_t stream) {
    const float* x = (const float*)d_in[0];   // (256, 12)
    const float* w = (const float*)d_in[1];   // (96,)
    float* out = (float*)d_out;               // (256, 1)
    qcp_kernel<<<BATCH, BLOCK, 0, stream>>>(x, w, out);
}

// Round 14
// 62.760 us; speedup vs baseline: 1.1072x; 1.1072x over previous
//
#include <hip/hip_runtime.h>

#define NQ 12
#define NL 4
#define DIM 4096
#define BLOCK 512
#define PER_T 8           // amplitudes per thread
#define BATCH 256

// Layout A: i = lane | k<<6 | wv<<9   (lane: q6-11, k: q3-5, wv: q0-2)
// Layout B: i = lane | wv<<6 | k<<9   (lane: q6-11, wv: q3-5, k: q0-2)
// Qubit q lives at bit position 11-q of the global amplitude index.
//
// Layers 0,1: R11 structure (best measured): regs gates -> pass1 (A->B
// transpose + RY/RZ q6 2-pt fold) -> q0-2 reg gates -> pass2 (RY/RZ q7 fold
// + CX Gray perm, B->A).
// Layer 2: pass1 upgraded to a 4-pt fold applying BOTH q6,q7 gates; pass2
// (CX perm) is skipped entirely.
// Layer 3: Z(0) commutes with every layer-3 gate except enc-RZ(q0), RY(q0)
// (CX: q0 only a control; RZ: diagonal; RY(q!=0): block-diag in q0). So
// <Z> = cos(th)*Sum(|a0|^2-|a1|^2) - 2 sin(th)*Sum Re(a0*conj(a1)*e^{-i x0}),
// th = w[3,0,0], over pairs of psi_2. Layer-2's skipped CX perm maps pairs
// (j, j^0x800) -> (i, i^0xC00); in layout B i^0xC00 = k^6: REGISTER-LOCAL.

__device__ __forceinline__ float2 cmul(float2 a, float2 b) {
    return make_float2(a.x * b.x - a.y * b.y, a.x * b.y + a.y * b.x);
}
__device__ __forceinline__ float2 cconj(float2 a) { return make_float2(a.x, -a.y); }

// HW sincos (revolutions, fract-reduced); |err| ~1e-6 << 1.37e-2 threshold.
__device__ __forceinline__ float2 fsincos(float ang) {   // (cos, sin)
    float r = ang * 0.15915494309189535f;
    r = r - floorf(r);
    return make_float2(__builtin_amdgcn_cosf(r), __builtin_amdgcn_sinf(r));
}

// ---- DPP lane exchanges (VALU pipe, intrinsic-only) -----------------------
// quad_perm xor1 = 0xB1, xor2 = 0x4E, xor3 = 0x1B; row_ror:8 = xor8 = 0x128;
// row_half_mirror = xor7 = 0x141.  xor4 = 0x141 then 0x1B.
template <int CTRL>
__device__ __forceinline__ float dppx(float v) {
    int i = __builtin_bit_cast(int, v);
    int r = __builtin_amdgcn_update_dpp(0, i, CTRL, 0xF, 0xF, true);
    return __builtin_bit_cast(float, r);
}
template <int MSK, int CTRL>
__device__ __forceinline__ void ry_dpp(float2* psi, int lane, float c, float s) {
    const float se = (lane & MSK) ? s : -s;
#pragma unroll
    for (int k = 0; k < PER_T; ++k) {
        float px = dppx<CTRL>(psi[k].x);
        float py = dppx<CTRL>(psi[k].y);
        psi[k].x = c * psi[k].x + se * px;
        psi[k].y = c * psi[k].y + se * py;
    }
}
__device__ __forceinline__ void ry_dpp4(float2* psi, int lane, float c, float s) {
    const float se = (lane & 4) ? s : -s;
#pragma unroll
    for (int k = 0; k < PER_T; ++k) {
        float px = dppx<0x1B>(dppx<0x141>(psi[k].x));
        float py = dppx<0x1B>(dppx<0x141>(psi[k].y));
        psi[k].x = c * psi[k].x + se * px;
        psi[k].y = c * psi[k].y + se * py;
    }
}

__global__ __launch_bounds__(BLOCK, 2) void qcp_kernel(
    const float* __restrict__ x,      // (BATCH, NQ)
    const float* __restrict__ w,      // (NL, NQ, 2) flat: [ry, rz] -> 96
    float* __restrict__ out)          // (BATCH,)
{
    __shared__ float2 sP[DIM];             // pass-1 staging
    __shared__ float2 sQ[DIM];             // pass-2 staging
    __shared__ float2 trig[NL * NQ * 2];   // (cos, sin) of 0.5*w[idx]
    __shared__ float  zhalf[NL * NQ];      // 0.5 * rz weight
    __shared__ float  rbuf[8];

    const int b    = blockIdx.x;
    const int t    = threadIdx.x;
    const int lane = t & 63;
    const int wv   = t >> 6;               // 0..7

    if (t < NL * NQ * 2) trig[t] = fsincos(0.5f * w[t]);
    if (t < NL * NQ) zhalf[t] = 0.5f * w[2 * t + 1];

    float xr[NQ];
#pragma unroll
    for (int q = 0; q < NQ; ++q) xr[q] = x[b * NQ + q];

    // Thread-constant addresses.
    int iA[PER_T], iB[PER_T], gI[PER_T];
#pragma unroll
    for (int k = 0; k < PER_T; ++k) {
        iA[k] = lane | (k << 6) | (wv << 9);
        iB[k] = lane | (wv << 6) | (k << 9);
        gI[k] = iA[k] ^ (iA[k] >> 1);
    }

    // Data-encoding phasors for the layout-A set (identical each layer).
    float2 eph[PER_T];
#pragma unroll
    for (int k = 0; k < PER_T; ++k) {
        int j = iA[k];
        float ang = 0.0f;
#pragma unroll
        for (int q = 0; q < NQ; ++q)
            ang += ((j >> (NQ - 1 - q)) & 1) ? 0.5f * xr[q] : -0.5f * xr[q];
        eph[k] = fsincos(ang);
    }

    float2 psi[PER_T];
#pragma unroll
    for (int k = 0; k < PER_T; ++k) psi[k] = make_float2(0.015625f, 0.0f);

    __syncthreads();   // trig/zhalf ready

    // ======================= layers 0,1: full R11 ==========================
    for (int l = 0; l < 2; ++l) {
        float2 tRY[9];          // RY (c,s) for q=3..11
        float2 tRY0[3], tZ0[3]; // q=0..2 RY and RZ pairs
        float  zh[4];           // 0.5*rz for q=8..11
        float2 z3, z4, z5, z6, z7;
#pragma unroll
        for (int q = 3; q <= 11; ++q) tRY[q - 3] = trig[(l * NQ + q) * 2];
#pragma unroll
        for (int q = 0; q < 3; ++q) {
            tRY0[q] = trig[(l * NQ + q) * 2 + 0];
            tZ0[q]  = trig[(l * NQ + q) * 2 + 1];
        }
        z3 = trig[(l * NQ + 3) * 2 + 1];
        z4 = trig[(l * NQ + 4) * 2 + 1];
        z5 = trig[(l * NQ + 5) * 2 + 1];
        z6 = trig[(l * NQ + 6) * 2 + 1];
        z7 = trig[(l * NQ + 7) * 2 + 1];
#pragma unroll
        for (int q = 8; q <= 11; ++q) zh[q - 8] = zhalf[l * NQ + q];

        // 1) encoding diagonal
#pragma unroll
        for (int k = 0; k < PER_T; ++k) psi[k] = cmul(psi[k], eph[k]);

        // 2) RY q3..5 on k bits
#pragma unroll
        for (int q = 3; q <= 5; ++q) {
            const int kb = (11 - q) - 6;
            float c = tRY[q - 3].x, s = tRY[q - 3].y;
#pragma unroll
            for (int m = 0; m < PER_T / 2; ++m) {
                int k0 = ((m >> kb) << (kb + 1)) | (m & ((1 << kb) - 1));
                int k1 = k0 | (1 << kb);
                float2 a0 = psi[k0], a1 = psi[k1];
                psi[k0] = make_float2(c * a0.x - s * a1.x, c * a0.y - s * a1.y);
                psi[k1] = make_float2(s * a0.x + c * a1.x, s * a0.y + c * a1.y);
            }
        }

        // 3) RY q8..11 on lane bits (DPP)
        ry_dpp<8, 0x128>(psi, lane, tRY[5].x, tRY[5].y);
        ry_dpp4(psi, lane, tRY[6].x, tRY[6].y);
        ry_dpp<2, 0x4E>(psi, lane, tRY[7].x, tRY[7].y);
        ry_dpp<1, 0xB1>(psi, lane, tRY[8].x, tRY[8].y);

        // 4) fused RZ diagonal q3..5, q8..11
        float s_lane = 0.0f;
#pragma unroll
        for (int p = 0; p < 4; ++p)
            s_lane += ((lane >> p) & 1) ? zh[3 - p] : -zh[3 - p];
        {
            float2 base = fsincos(s_lane);
            float2 z45[4];
#pragma unroll
            for (int c2 = 0; c2 < 4; ++c2) {
                float2 a4 = (c2 & 2) ? z4 : cconj(z4);
                float2 a5 = (c2 & 1) ? z5 : cconj(z5);
                z45[c2] = cmul(a4, a5);
            }
#pragma unroll
            for (int k = 0; k < PER_T; ++k) {
                float2 a3 = (k & 4) ? z3 : cconj(z3);
                float2 ph = cmul(cmul(base, a3), z45[k & 3]);
                psi[k] = cmul(psi[k], ph);
            }
        }

        // 5) pass 1: A->B transpose + RY/RZ(q6) 2-pt fold (bit5)
#pragma unroll
        for (int k = 0; k < PER_T; ++k) sP[iA[k]] = psi[k];
        const int   b6  = (lane >> 5) & 1;
        const float c6  = tRY[3].x;
        const float se6 = b6 ? tRY[3].y : -tRY[3].y;
        const float2 zb6 = b6 ? z6 : cconj(z6);
        __syncthreads();
#pragma unroll
        for (int k = 0; k < PER_T; ++k) {
            float2 own = sP[iB[k]];
            float2 oth = sP[iB[k] ^ 32];
            float2 n = make_float2(c6 * own.x + se6 * oth.x,
                                   c6 * own.y + se6 * oth.y);
            psi[k] = cmul(n, zb6);
        }

        // 6) RY+RZ q0..2 on k bits
#pragma unroll
        for (int q = 0; q < 3; ++q) {
            const int kb = 2 - q;
            float c = tRY0[q].x, s = tRY0[q].y;
            float2 z = tZ0[q];
#pragma unroll
            for (int m = 0; m < PER_T / 2; ++m) {
                int k0 = ((m >> kb) << (kb + 1)) | (m & ((1 << kb) - 1));
                int k1 = k0 | (1 << kb);
                float2 a0 = psi[k0], a1 = psi[k1];
                float2 n0 = make_float2(c * a0.x - s * a1.x, c * a0.y - s * a1.y);
                float2 n1 = make_float2(s * a0.x + c * a1.x, s * a0.y + c * a1.y);
                psi[k0] = cmul(n0, cconj(z));
                psi[k1] = cmul(n1, z);
            }
        }

        // 7) pass 2: RY/RZ(q7) fold (bit4 of g) + CX Gray perm, B->A
#pragma unroll
        for (int k = 0; k < PER_T; ++k) sQ[iB[k]] = psi[k];
        const int   b7  = ((lane >> 4) ^ (lane >> 5)) & 1;
        const float c7  = tRY[4].x;
        const float se7 = b7 ? tRY[4].y : -tRY[4].y;
        const float2 zb7 = b7 ? z7 : cconj(z7);
        __syncthreads();
#pragma unroll
        for (int k = 0; k < PER_T; ++k) {
            float2 own = sQ[gI[k]];
            float2 oth = sQ[gI[k] ^ 16];
            float2 n = make_float2(c7 * own.x + se7 * oth.x,
                                   c7 * own.y + se7 * oth.y);
            psi[k] = cmul(n, zb7);
        }
    }

    // ======================= layer 2 (no pass 2) ===========================
    {
        const int l = 2;
        float2 tRY[9];
        float2 tRY0[3], tZ0[3];
        float  zh[4];
        float2 z3, z4, z5, z6, z7;
#pragma unroll
        for (int q = 3; q <= 11; ++q) tRY[q - 3] = trig[(l * NQ + q) * 2];
#pragma unroll
        for (int q = 0; q < 3; ++q) {
            tRY0[q] = trig[(l * NQ + q) * 2 + 0];
            tZ0[q]  = trig[(l * NQ + q) * 2 + 1];
        }
        z3 = trig[(l * NQ + 3) * 2 + 1];
        z4 = trig[(l * NQ + 4) * 2 + 1];
        z5 = trig[(l * NQ + 5) * 2 + 1];
        z6 = trig[(l * NQ + 6) * 2 + 1];
        z7 = trig[(l * NQ + 7) * 2 + 1];
#pragma unroll
        for (int q = 8; q <= 11; ++q) zh[q - 8] = zhalf[l * NQ + q];

        // 1) encoding diagonal
#pragma unroll
        for (int k = 0; k < PER_T; ++k) psi[k] = cmul(psi[k], eph[k]);

        // 2) RY q3..5
#pragma unroll
        for (int q = 3; q <= 5; ++q) {
            const int kb = (11 - q) - 6;
            float c = tRY[q - 3].x, s = tRY[q - 3].y;
#pragma unroll
            for (int m = 0; m < PER_T / 2; ++m) {
                int k0 = ((m >> kb) << (kb + 1)) | (m & ((1 << kb) - 1));
                int k1 = k0 | (1 << kb);
                float2 a0 = psi[k0], a1 = psi[k1];
                psi[k0] = make_float2(c * a0.x - s * a1.x, c * a0.y - s * a1.y);
                psi[k1] = make_float2(s * a0.x + c * a1.x, s * a0.y + c * a1.y);
            }
        }

        // 3) RY q8..11 (DPP)
        ry_dpp<8, 0x128>(psi, lane, tRY[5].x, tRY[5].y);
        ry_dpp4(psi, lane, tRY[6].x, tRY[6].y);
        ry_dpp<2, 0x4E>(psi, lane, tRY[7].x, tRY[7].y);
        ry_dpp<1, 0xB1>(psi, lane, tRY[8].x, tRY[8].y);

        // 4) fused RZ diagonal q3..5, q8..11
        float s_lane = 0.0f;
#pragma unroll
        for (int p = 0; p < 4; ++p)
            s_lane += ((lane >> p) & 1) ? zh[3 - p] : -zh[3 - p];
        {
            float2 base = fsincos(s_lane);
            float2 z45[4];
#pragma unroll
            for (int c2 = 0; c2 < 4; ++c2) {
                float2 a4 = (c2 & 2) ? z4 : cconj(z4);
                float2 a5 = (c2 & 1) ? z5 : cconj(z5);
                z45[c2] = cmul(a4, a5);
            }
#pragma unroll
            for (int k = 0; k < PER_T; ++k) {
                float2 a3 = (k & 4) ? z3 : cconj(z3);
                float2 ph = cmul(cmul(base, a3), z45[k & 3]);
                psi[k] = cmul(psi[k], ph);
            }
        }

        // 5) pass 1': A->B transpose + 4-pt fold applying RY/RZ(q6) AND
        //    RY/RZ(q7). Source = iB with bits 5,4 replaced by (c6,c7).
        //    Real RY weights w[c6][c7] = r6[c6]*r7[c7]; row RZ phase
        //    zb67 = zb6*zb7 factored out (thread-uniform).
#pragma unroll
        for (int k = 0; k < PER_T; ++k) sP[iA[k]] = psi[k];
        const int b6 = (lane >> 5) & 1;
        const int b7 = (lane >> 4) & 1;
        const float c6v = tRY[3].x, s6 = tRY[3].y;
        const float c7v = tRY[4].x, s7 = tRY[4].y;
        const float r6c0 = b6 ? s6 : c6v,  r6c1 = b6 ? c6v : -s6;
        const float r7c0 = b7 ? s7 : c7v,  r7c1 = b7 ? c7v : -s7;
        const float w00 = r6c0 * r7c0, w01 = r6c0 * r7c1;
        const float w10 = r6c1 * r7c0, w11 = r6c1 * r7c1;
        const float2 zb67 = cmul(b6 ? z6 : cconj(z6), b7 ? z7 : cconj(z7));
        __syncthreads();
#pragma unroll
        for (int k = 0; k < PER_T; ++k) {
            int base = iB[k] & ~0x30;
            float2 v00 = sP[base];
            float2 v01 = sP[base | 0x10];
            float2 v10 = sP[base | 0x20];
            float2 v11 = sP[base | 0x30];
            float nx = w00 * v00.x + w01 * v01.x + w10 * v10.x + w11 * v11.x;
            float ny = w00 * v00.y + w01 * v01.y + w10 * v10.y + w11 * v11.y;
            psi[k] = cmul(make_float2(nx, ny), zb67);
        }

        // 6) RY+RZ q0..2 on k bits
#pragma unroll
        for (int q = 0; q < 3; ++q) {
            const int kb = 2 - q;
            float c = tRY0[q].x, s = tRY0[q].y;
            float2 z = tZ0[q];
#pragma unroll
            for (int m = 0; m < PER_T / 2; ++m) {
                int k0 = ((m >> kb) << (kb + 1)) | (m & ((1 << kb) - 1));
                int k1 = k0 | (1 << kb);
                float2 a0 = psi[k0], a1 = psi[k1];
                float2 n0 = make_float2(c * a0.x - s * a1.x, c * a0.y - s * a1.y);
                float2 n1 = make_float2(s * a0.x + c * a1.x, s * a0.y + c * a1.y);
                psi[k0] = cmul(n0, cconj(z));
                psi[k1] = cmul(n1, z);
            }
        }
        // layer-2 CX perm is folded into the measurement pairing below.
    }

    // ================= layer 3 collapsed into measurement ==================
    // Pairs of psi_2 under layer-2's CX perm: (i, i^0xC00) = regs (k, k^6).
    // a0 = q0=0 member (k&4 == 0). th = w[3,0,0]; enc phase x0.
    // <Z> = cos(th)*Sum diff - 2 sin(th)*Sum Re(a0*conj(a1)*e^{-i x0}).
    float diff = 0.0f, cross = 0.0f;
    {
        float2 e0 = fsincos(xr[0]);               // (cos x0, sin x0)
#pragma unroll
        for (int k = 0; k < 4; ++k) {
            float2 a0 = psi[k];
            float2 a1 = psi[k ^ 6];
            diff += (a0.x * a0.x + a0.y * a0.y) - (a1.x * a1.x + a1.y * a1.y);
            float px = a0.x * a1.x + a0.y * a1.y;   // Re(a0*conj(a1))
            float py = a0.y * a1.x - a0.x * a1.y;   // Im(a0*conj(a1))
            cross += px * e0.x + py * e0.y;         // Re(a0*conj(a1)*e^{-ix0})
        }
    }
    float2 t30 = trig[(3 * NQ + 0) * 2];          // (cos(th/2), sin(th/2))
    float costh = t30.x * t30.x - t30.y * t30.y;
    float sinth = 2.0f * t30.x * t30.y;
    float acc = costh * diff - 2.0f * sinth * cross;

#pragma unroll
    for (int off = 32; off > 0; off >>= 1)
        acc += __shfl_down(acc, off, 64);
    if (lane == 0) rbuf[wv] = acc;
    __syncthreads();
    if (t == 0) {
        float tot = 0.0f;
#pragma unroll
        for (int i = 0; i < 8; ++i) tot += rbuf[i];
        out[b] = tot;
    }
}

extern "C" void kernel_launch(void* const* d_in, const int* in_sizes, int n_in,
                              void* d_out, int out_size, void* d_ws, size_t ws_size,
                              hipStream_t stream) {
    const float* x = (const float*)d_in[0];   // (256, 12)
    const float* w = (const float*)d_in[1];   // (96,)
    float* out = (float*)d_out;               // (256, 1)
    qcp_kernel<<<BATCH, BLOCK, 0, stream>>>(x, w, out);
}

// Round 15
// 57.469 us; speedup vs baseline: 1.2092x; 1.0921x over previous
//
#include <hip/hip_runtime.h>

#define NQ 12
#define NL 4
#define BATCH 256

// Light-cone reduction (Heisenberg picture), validated empirically by R13:
//   O = Z0. The CX ladder CX(q,q+1) q=0..10 satisfies:
//     Z0 commutes with the whole ladder (q0 only a control);
//     X0/Y0 -> X0X1/Y0X1 via CX(0,1) only; X1 -> X1X2 via CX(1,2); ...
//   So conjugating Z0 backward through the circuit, the observable support is
//     layer 3: {q0}, layer 2: {q0,q1}, layer 1: {q0..q2}, layer 0: {q0..q3}.
//   Gates on qubits outside the support commute with O and cancel exactly.
//   Initial state |+>^12 is product, final observable supported on q0..q3 =>
//   <Z0> equals the same quantity computed in the reduced 4-QUBIT circuit:
//     init |+>^4
//     layer l (l=0..3): enc RZ(x_q) for q=0..3-l; (RY,RZ)(w[l,q]) q=0..3-l;
//                       CX(0,1)..CX(2-l,3-l)   [layer 3: no CX]
//     E = sum_j (-1)^{bit_q0(j)} |a_j|^2.
// 16 amplitudes/thread, one thread per batch sample. No LDS, no barriers,
// no cross-lane traffic. ~600 FLOP + 24 HW sincos per sample.

__device__ __forceinline__ float2 fsincos(float ang) {   // (cos, sin)
    float r = ang * 0.15915494309189535f;                // rad -> rev
    r = r - floorf(r);
    return make_float2(__builtin_amdgcn_cosf(r), __builtin_amdgcn_sinf(r));
}

__global__ __launch_bounds__(64) void qcp_kernel(
    const float* __restrict__ x,      // (BATCH, NQ)
    const float* __restrict__ w,      // (NL, NQ, 2) flat: [ry, rz]
    float* __restrict__ out)          // (BATCH,)
{
    const int b = blockIdx.x * 64 + threadIdx.x;   // 0..255, one sample/thread

    float xr[4];
#pragma unroll
    for (int q = 0; q < 4; ++q) xr[q] = x[b * NQ + q];

    // 4-qubit state; qubit q <-> bit (3-q) of the index (matches the
    // full-kernel convention qubit q <-> bit (NQ-1-q)).
    float2 a[16];
#pragma unroll
    for (int j = 0; j < 16; ++j) a[j] = make_float2(0.25f, 0.0f);

#pragma unroll
    for (int l = 0; l < NL; ++l) {
        const int nk = 4 - l;                  // kept qubits 0..nk-1

        // ---- 1) encoding RZ(x_q) on kept qubits ----------------------------
        // RZ(t) = diag(e^{-it/2}, e^{+it/2})
#pragma unroll
        for (int q = 0; q < 4; ++q) {
            if (q >= nk) break;                // folds at compile time
            const int m = 1 << (3 - q);
            float2 ph = fsincos(0.5f * xr[q]); // (cos, sin)
#pragma unroll
            for (int j = 0; j < 16; ++j) {
                float si = (j & m) ? ph.y : -ph.y;
                float2 v = a[j];
                a[j] = make_float2(v.x * ph.x - v.y * si,
                                   v.y * ph.x + v.x * si);
            }
        }

        // ---- 2) RY then RZ per kept qubit ----------------------------------
#pragma unroll
        for (int q = 0; q < 4; ++q) {
            if (q >= nk) break;
            const int m = 1 << (3 - q);
            float2 ry = fsincos(0.5f * w[(l * NQ + q) * 2 + 0]);
            float2 rz = fsincos(0.5f * w[(l * NQ + q) * 2 + 1]);
#pragma unroll
            for (int j = 0; j < 16; ++j) {
                if (j & m) continue;
                float2 a0 = a[j], a1 = a[j | m];
                // RY: [[c,-s],[s,c]]
                float2 n0 = make_float2(ry.x * a0.x - ry.y * a1.x,
                                        ry.x * a0.y - ry.y * a1.y);
                float2 n1 = make_float2(ry.y * a0.x + ry.x * a1.x,
                                        ry.y * a0.y + ry.x * a1.y);
                // RZ: n0 *= (c,-s); n1 *= (c,+s)
                a[j]     = make_float2(n0.x * rz.x + n0.y * rz.y,
                                       n0.y * rz.x - n0.x * rz.y);
                a[j | m] = make_float2(n1.x * rz.x - n1.y * rz.y,
                                       n1.y * rz.x + n1.x * rz.y);
            }
        }

        // ---- 3) partial ladder CX(q,q+1), q = 0..nk-2 ----------------------
        // psi'[j] = psi[j ^ tmask] where control bit set: swap the pair.
#pragma unroll
        for (int q = 0; q < 3; ++q) {
            if (q >= nk - 1) break;
            const int cm = 1 << (3 - q);
            const int tm = 1 << (2 - q);
#pragma unroll
            for (int j = 0; j < 16; ++j) {
                if ((j & cm) && !(j & tm)) {
                    float2 tmp = a[j];
                    a[j] = a[j | tm];
                    a[j | tm] = tmp;
                }
            }
        }
    }

    // ---- <Z(0)>: qubit 0 = bit 3 ------------------------------------------
    float e = 0.0f;
#pragma unroll
    for (int j = 0; j < 16; ++j) {
        float p = a[j].x * a[j].x + a[j].y * a[j].y;
        e += (j & 8) ? -p : p;
    }
    out[b] = e;
}

extern "C" void kernel_launch(void* const* d_in, const int* in_sizes, int n_in,
                              void* d_out, int out_size, void* d_ws, size_t ws_size,
                              hipStream_t stream) {
    const float* x = (const float*)d_in[0];   // (256, 12)
    const float* w = (const float*)d_in[1];   // (96,)
    float* out = (float*)d_out;               // (256, 1)
    qcp_kernel<<<BATCH / 64, 64, 0, stream>>>(x, w, out);
}